// Round 1
// baseline (435.097 us; speedup 1.0000x reference)
//
#include <hip/hip_runtime.h>

#define HH 128
#define WW 128
#define CC 64
#define TT 5
#define HW (HH*WW)

// ---------------- conv1: 64->64 3x3 zero-pad + leaky relu ----------------
// grid (8,8, n*4+ocg), block (16,16). Each block: 16x16 tile, 16 output chans.
__global__ __launch_bounds__(256) void conv1_k(const float* __restrict__ x,
    const float* __restrict__ w1, const float* __restrict__ b1,
    float* __restrict__ y) {
  __shared__ float tile[18*18];
  const int tw = threadIdx.x, th = threadIdx.y;
  const int tid = th*16 + tw;
  const int wz = blockIdx.z;
  const int n = wz >> 2, ocg = (wz & 3) << 4;
  const int bi = n / 5, ti = n % 5;
  const int h0 = blockIdx.y << 4, w0 = blockIdx.x << 4;
  const float* xn = x + ((size_t)bi*CC*TT + ti) * HW;   // + ic*TT*HW

  float acc[16];
  #pragma unroll
  for (int o = 0; o < 16; ++o) acc[o] = b1[ocg + o];

  for (int ic = 0; ic < CC; ++ic) {
    __syncthreads();
    for (int e = tid; e < 18*18; e += 256) {
      int r = e / 18, c = e - r*18;
      int gh = h0 + r - 1, gw = w0 + c - 1;
      float v = 0.f;
      if (gh >= 0 && gh < HH && gw >= 0 && gw < WW)
        v = xn[(size_t)ic*(TT*HW) + gh*WW + gw];
      tile[e] = v;
    }
    __syncthreads();
    float p[9];
    #pragma unroll
    for (int i = 0; i < 3; ++i)
      #pragma unroll
      for (int j = 0; j < 3; ++j)
        p[i*3+j] = tile[(th+i)*18 + tw + j];
    const float* wp = w1 + ((size_t)ocg*CC + ic)*9;  // block-uniform -> s_load
    #pragma unroll
    for (int o = 0; o < 16; ++o) {
      #pragma unroll
      for (int k = 0; k < 9; ++k)
        acc[o] = fmaf(wp[o*CC*9 + k], p[k], acc[o]);
    }
  }
  float* yp = y + ((size_t)n*CC + ocg)*HW + (h0+th)*WW + w0 + tw;
  #pragma unroll
  for (int o = 0; o < 16; ++o) {
    float v = acc[o];
    yp[(size_t)o*HW] = (v >= 0.f) ? v : 0.2f*v;
  }
}

// ---------------- conv2: 64->9 3x3 zero-pad (raw kernel, un-normalized) ----
// grid (8,8,10), block (16,16). Output layout (n, kk, h, w).
__global__ __launch_bounds__(256) void conv2_k(const float* __restrict__ y,
    const float* __restrict__ w2, const float* __restrict__ b2,
    float* __restrict__ ker0) {
  __shared__ float tile[18*18];
  const int tw = threadIdx.x, th = threadIdx.y;
  const int tid = th*16 + tw;
  const int n = blockIdx.z;
  const int h0 = blockIdx.y << 4, w0 = blockIdx.x << 4;
  const float* yn = y + (size_t)n*CC*HW;

  float acc[9];
  #pragma unroll
  for (int o = 0; o < 9; ++o) acc[o] = b2[o];

  for (int ic = 0; ic < CC; ++ic) {
    __syncthreads();
    for (int e = tid; e < 18*18; e += 256) {
      int r = e / 18, c = e - r*18;
      int gh = h0 + r - 1, gw = w0 + c - 1;
      float v = 0.f;
      if (gh >= 0 && gh < HH && gw >= 0 && gw < WW)
        v = yn[(size_t)ic*HW + gh*WW + gw];
      tile[e] = v;
    }
    __syncthreads();
    float p[9];
    #pragma unroll
    for (int i = 0; i < 3; ++i)
      #pragma unroll
      for (int j = 0; j < 3; ++j)
        p[i*3+j] = tile[(th+i)*18 + tw + j];
    const float* wp = w2 + (size_t)ic*9;
    #pragma unroll
    for (int o = 0; o < 9; ++o) {
      #pragma unroll
      for (int k = 0; k < 9; ++k)
        acc[o] = fmaf(wp[o*CC*9 + k], p[k], acc[o]);
    }
  }
  float* kp = ker0 + (size_t)n*9*HW + (h0+th)*WW + w0 + tw;
  #pragma unroll
  for (int o = 0; o < 9; ++o) kp[(size_t)o*HW] = acc[o];
}

// ---------------- dynamic filtering -----------------------------------------
// out[bi,ci,h,w] = sum_{ti,i,j} x_edgeclamped[bi,ci,ti,h+i-1,w+j-1]
//                               * (ker0 - mean_K + 1/45)[bi,h,w,ti*9+i*3+j]
// grid (8,8, bi*4+cig), block (16,16): 16x16 tile, 16 channels per block.
__global__ __launch_bounds__(256) void dynf_k(const float* __restrict__ x,
    const float* __restrict__ ker0, float* __restrict__ out) {
  __shared__ float xt[TT*324];
  const int tw = threadIdx.x, th = threadIdx.y;
  const int tid = th*16 + tw;
  const int wz = blockIdx.z;
  const int bi = wz >> 2, cig = (wz & 3) << 4;
  const int h0 = blockIdx.y << 4, w0 = blockIdx.x << 4;
  const int pix = (h0+th)*WW + w0 + tw;

  // load this pixel's 45 raw kernel values, normalize in-register
  float kv[45];
  float s = 0.f;
  #pragma unroll
  for (int ti = 0; ti < TT; ++ti)
    #pragma unroll
    for (int kk = 0; kk < 9; ++kk) {
      float v = ker0[((size_t)(bi*TT + ti)*9 + kk)*HW + pix];
      kv[ti*9+kk] = v;
      s += v;
    }
  const float m = (s - 1.f) * (1.f/45.f);   // mean - 1/45
  #pragma unroll
  for (int q = 0; q < 45; ++q) kv[q] -= m;

  for (int c = 0; c < 16; ++c) {
    const int ci = cig + c;
    const float* xc = x + ((size_t)(bi*CC + ci))*TT*HW;
    __syncthreads();
    for (int e = tid; e < TT*324; e += 256) {
      int tt = e / 324, r2 = e - tt*324;
      int r = r2 / 18, cc = r2 - r*18;
      int gh = min(max(h0 + r - 1, 0), HH-1);
      int gw = min(max(w0 + cc - 1, 0), WW-1);
      xt[e] = xc[(size_t)tt*HW + gh*WW + gw];
    }
    __syncthreads();
    float acc = 0.f;
    #pragma unroll
    for (int tt = 0; tt < TT; ++tt)
      #pragma unroll
      for (int i = 0; i < 3; ++i)
        #pragma unroll
        for (int j = 0; j < 3; ++j)
          acc = fmaf(xt[tt*324 + (th+i)*18 + tw + j], kv[tt*9 + i*3 + j], acc);
    out[((size_t)(bi*CC + ci))*HW + pix] = acc;
  }
}

extern "C" void kernel_launch(void* const* d_in, const int* in_sizes, int n_in,
                              void* d_out, int out_size, void* d_ws, size_t ws_size,
                              hipStream_t stream) {
  const float* x  = (const float*)d_in[0];
  const float* w1 = (const float*)d_in[1];
  const float* b1 = (const float*)d_in[2];
  const float* w2 = (const float*)d_in[3];
  const float* b2 = (const float*)d_in[4];
  float* out = (float*)d_out;

  float* y    = (float*)d_ws;                       // 10*64*16384 fp32 = 40 MiB
  float* ker0 = y + (size_t)10*CC*HW;               // 10*9*16384 fp32 = 5.6 MiB

  conv1_k<<<dim3(8,8,40), dim3(16,16), 0, stream>>>(x, w1, b1, y);
  conv2_k<<<dim3(8,8,10), dim3(16,16), 0, stream>>>(y, w2, b2, ker0);
  dynf_k <<<dim3(8,8, 8), dim3(16,16), 0, stream>>>(x, ker0, out);
}